// Round 3
// baseline (622.710 us; speedup 1.0000x reference)
//
#include <hip/hip_runtime.h>

#define HID 30
#define TS  512
#define WPB 4   // waves (= batch elements) per 256-thread block
#define LOG2E 1.44269504088896340736f

typedef float v2f __attribute__((ext_vector_type(2)));

__device__ __forceinline__ v2f pk_fma(v2f a, v2f b, v2f c) {
    v2f d;
    asm("v_pk_fma_f32 %0, %1, %2, %3" : "=v"(d) : "v"(a), "v"(b), "v"(c));
    return d;
}
__device__ __forceinline__ v2f pk_add(v2f a, v2f b) {
    v2f d;
    asm("v_pk_add_f32 %0, %1, %2" : "=v"(d) : "v"(a), "v"(b));
    return d;
}

__global__ __launch_bounds__(256, 4)
void lstm_kernel(const float* __restrict__ batch,
                 const float* __restrict__ W_ih,
                 const float* __restrict__ W_hh,
                 const float* __restrict__ b_ih,
                 const float* __restrict__ b_hh,
                 const float* __restrict__ W_fc,
                 const float* __restrict__ b_fc,
                 float* __restrict__ out)
{
    __shared__ float xs[WPB][TS];   // 8 KB: x rows, one per wave
    __shared__ float hs[WPB][32];   // h state per wave (slots 30,31 unused-dup)

    const int tid  = threadIdx.x;
    const int w    = tid >> 6;          // wave id in block
    const int lane = tid & 63;
    const int half = lane >> 5;         // 0: gates i,f   1: gates g,o
    const int j    = lane & 31;         // hidden unit (j<30 active)
    const int jj   = (j < HID) ? j : (HID - 1);
    const int b    = blockIdx.x * WPB + w;

    // ---- per-wave x staging (coalesced; wave-private -> no barrier) ----
    const float* src = batch + (size_t)b * TS;
    #pragma unroll
    for (int i = 0; i < TS / 64; ++i)
        xs[w][lane + i * 64] = src[lane + i * 64];

    hs[w][j] = 0.0f;   // init h (both halves write same slot: benign)

    // ---- per-lane weights as aligned k-pairs (rows are 120B, 8B-aligned) --
    const int row0 = jj + (half ? 2 * HID : 0);   // gate i (half0) / g (half1)
    const int row1 = row0 + HID;                  // gate f (half0) / o (half1)
    const v2f* wr0 = (const v2f*)(W_hh + row0 * HID);
    const v2f* wr1 = (const v2f*)(W_hh + row1 * HID);
    v2f w0p[15], w1p[15];
    #pragma unroll
    for (int p = 0; p < 15; ++p) { w0p[p] = wr0[p]; w1p[p] = wr1[p]; }

    const float bb0 = b_ih[row0] + b_hh[row0];
    const float bb1 = b_ih[row1] + b_hh[row1];
    const float xw0 = W_ih[row0];
    const float xw1 = W_ih[row1];

    // act0 = half ? tanh(a0) : sigm(a0)  -- merged, divergence-free
    const float m0  = half ? 2.0f : 1.0f;
    const float ad0 = half ? -1.0f : 0.0f;
    const float nm0 = -m0 * LOG2E;
    const int swap4 = (lane ^ 32) << 2;   // bpermute partner (other half)

    float c = 0.0f;

    for (int t = 0; t < TS; ++t) {
        const float x = xs[w][t];                       // uniform broadcast
        v2f acc0a = { fmaf(x, xw0, bb0), 0.0f };
        v2f acc0b = { 0.0f, 0.0f };
        v2f acc1a = { fmaf(x, xw1, bb1), 0.0f };
        v2f acc1b = { 0.0f, 0.0f };

        // h dot products: 8x ds_read_b128 (uniform -> broadcast), 30 pk_fma
        #pragma unroll
        for (int kb = 0; kb < 8; ++kb) {
            const float4 hq = ((const float4*)hs[w])[kb];
            const v2f hlo = { hq.x, hq.y };   // aligned sub-pair of the quad
            const v2f hhi = { hq.z, hq.w };
            const int p0 = 2 * kb, p1 = 2 * kb + 1;
            if (p0 < 15) {
                acc0a = pk_fma(hlo, w0p[p0], acc0a);
                acc1a = pk_fma(hlo, w1p[p0], acc1a);
            }
            if (p1 < 15) {
                acc0b = pk_fma(hhi, w0p[p1], acc0b);
                acc1b = pk_fma(hhi, w1p[p1], acc1b);
            }
        }
        const v2f s0v = pk_add(acc0a, acc0b);
        const v2f s1v = pk_add(acc1a, acc1b);
        const float a0 = s0v.x + s0v.y;
        const float a1 = s1v.x + s1v.y;

        const float r0c  = __builtin_amdgcn_rcpf(1.0f + exp2f(a0 * nm0));
        const float act0 = fmaf(r0c, m0, ad0);                         // i | g
        const float act1 = __builtin_amdgcn_rcpf(1.0f + exp2f(a1 * (-LOG2E))); // f | o

        // exchange with partner half
        const float r0 = __int_as_float(__builtin_amdgcn_ds_bpermute(swap4, __float_as_int(act0)));
        const float r1 = __int_as_float(__builtin_amdgcn_ds_bpermute(swap4, __float_as_int(act1)));

        const float prod = act0 * r0;            // i*g on BOTH halves
        const float fv   = half ? r1 : act1;     // forget gate
        const float ov   = half ? act1 : r1;     // output gate
        c = fmaf(fv, c, prod);
        const float th = fmaf(-2.0f,
            __builtin_amdgcn_rcpf(1.0f + exp2f(c * (2.0f * LOG2E))), 1.0f);
        hs[w][j] = ov * th;   // both halves write identical value
    }

    // ---- final projection: out[b] = b_fc + h . W_fc ----
    if (lane == 0) {
        float acc = b_fc[0];
        #pragma unroll
        for (int k = 0; k < HID; ++k)
            acc = fmaf(hs[w][k], W_fc[k], acc);
        out[b] = acc;
    }
}

extern "C" void kernel_launch(void* const* d_in, const int* in_sizes, int n_in,
                              void* d_out, int out_size, void* d_ws, size_t ws_size,
                              hipStream_t stream) {
    const float* batch = (const float*)d_in[0];
    const float* W_ih  = (const float*)d_in[1];
    const float* W_hh  = (const float*)d_in[2];
    const float* b_ih  = (const float*)d_in[3];
    const float* b_hh  = (const float*)d_in[4];
    const float* W_fc  = (const float*)d_in[5];
    const float* b_fc  = (const float*)d_in[6];
    float* out = (float*)d_out;

    const int blocks = 8192 / WPB;   // 2048
    lstm_kernel<<<blocks, 256, 0, stream>>>(batch, W_ih, W_hh, b_ih, b_hh,
                                            W_fc, b_fc, out);
}

// Round 4
// 543.072 us; speedup vs baseline: 1.1466x; 1.1466x over previous
//
#include <hip/hip_runtime.h>

#define HID 30
#define TS  512
#define WPB 4   // waves (= batch elements) per 256-thread block
#define LOG2E 1.44269504088896340736f

__global__ __launch_bounds__(256, 5)
void lstm_kernel(const float* __restrict__ batch,
                 const float* __restrict__ W_ih,
                 const float* __restrict__ W_hh,
                 const float* __restrict__ b_ih,
                 const float* __restrict__ b_hh,
                 const float* __restrict__ W_fc,
                 const float* __restrict__ b_fc,
                 float* __restrict__ out)
{
    __shared__ float xs[WPB][TS];   // 8 KB: x rows, one per wave
    __shared__ float hs[WPB][32];   // h state per wave (slots 30,31 unused)

    const int tid  = threadIdx.x;
    const int w    = tid >> 6;          // wave id in block
    const int lane = tid & 63;
    const int half = lane >> 5;         // 0: gates i,f   1: gates g,o
    const int j    = lane & 31;         // hidden unit (j<30 active)
    const int jj   = (j < HID) ? j : (HID - 1);
    const int b    = blockIdx.x * WPB + w;

    // ---- per-wave x staging (coalesced; wave-private -> no barrier) ----
    const float* src = batch + (size_t)b * TS;
    #pragma unroll
    for (int i = 0; i < TS / 64; ++i)
        xs[w][lane + i * 64] = src[lane + i * 64];

    hs[w][j] = 0.0f;   // init h

    // ---- per-lane weights, PRESCALED so activations need no pre-mul ----
    // row0: gate i (half0, sigmoid) / g (half1, tanh) ; row1: f / o (sigmoid)
    // sigmoid(a) = rcp(1 + exp2(-L*a));  tanh(a) = 2*rcp(1+exp2(-2L*a)) - 1
    // c is carried scaled by K = 2L: tanh(c) = fma(-2, rcp(1+exp2(c')), 1)
    const int   row0 = jj + (half ? 2 * HID : 0);
    const int   row1 = row0 + HID;
    const float s0   = half ? (-2.0f * LOG2E) : (-LOG2E);  // row0 prescale
    const float s1   = -LOG2E;                             // row1 prescale
    float w0[HID], w1[HID];
    #pragma unroll
    for (int k = 0; k < HID; ++k) {
        w0[k] = W_hh[row0 * HID + k] * s0;
        w1[k] = W_hh[row1 * HID + k] * s1;
    }
    const float bb0 = (b_ih[row0] + b_hh[row0]) * s0;
    const float bb1 = (b_ih[row1] + b_hh[row1]) * s1;
    const float xw0 = W_ih[row0] * s0;
    const float xw1 = W_ih[row1] * s1;

    // merged activation for a0:  act0 = fma(am, r0c, aa)
    //   half0: K*sigm -> am = 2L, aa = 0   (K-scaled i, feeds scaled c)
    //   half1: tanh   -> am = 2,  aa = -1  (g)
    const float am = half ? 2.0f : (2.0f * LOG2E);
    const float aa = half ? -1.0f : 0.0f;
    const int swap4 = (lane ^ 32) << 2;   // bpermute partner (other half)

    float cp = 0.0f;   // c scaled by 2L

#define STEP(xv)                                                              \
    {                                                                         \
        const float x = (xv);                                                 \
        float a0a = fmaf(x, xw0, bb0), a0b = 0.0f;                            \
        float a1a = fmaf(x, xw1, bb1), a1b = 0.0f;                            \
        _Pragma("unroll")                                                     \
        for (int kb = 0; kb < 8; ++kb) {                                      \
            const float4 hq = ((const float4*)hs[w])[kb];                     \
            const int k0 = kb * 4;                                            \
            if (k0 + 0 < HID) { a0a = fmaf(hq.x, w0[k0+0], a0a);              \
                                a1a = fmaf(hq.x, w1[k0+0], a1a); }            \
            if (k0 + 1 < HID) { a0b = fmaf(hq.y, w0[k0+1], a0b);              \
                                a1b = fmaf(hq.y, w1[k0+1], a1b); }            \
            if (k0 + 2 < HID) { a0a = fmaf(hq.z, w0[k0+2], a0a);              \
                                a1a = fmaf(hq.z, w1[k0+2], a1a); }            \
            if (k0 + 3 < HID) { a0b = fmaf(hq.w, w0[k0+3], a0b);              \
                                a1b = fmaf(hq.w, w1[k0+3], a1b); }            \
        }                                                                     \
        const float a0 = a0a + a0b;                                           \
        const float a1 = a1a + a1b;                                           \
        const float r0c  = __builtin_amdgcn_rcpf(1.0f + exp2f(a0));           \
        const float act0 = fmaf(am, r0c, aa);            /* K*i | g  */       \
        const float act1 = __builtin_amdgcn_rcpf(1.0f + exp2f(a1)); /* f|o */ \
        const float r0 = __int_as_float(                                      \
            __builtin_amdgcn_ds_bpermute(swap4, __float_as_int(act0)));       \
        const float r1 = __int_as_float(                                      \
            __builtin_amdgcn_ds_bpermute(swap4, __float_as_int(act1)));       \
        const float fv = half ? r1 : act1;                                    \
        const float ov = half ? act1 : r1;                                    \
        const float prod = act0 * r0;                    /* K*i*g both */     \
        cp = fmaf(fv, cp, prod);                                              \
        const float th = fmaf(-2.0f,                                          \
            __builtin_amdgcn_rcpf(1.0f + exp2f(cp)), 1.0f);                   \
        hs[w][j] = ov * th;                                                   \
    }

    for (int t4 = 0; t4 < TS / 4; ++t4) {
        const float4 xq = ((const float4*)xs[w])[t4];
        STEP(xq.x)
        STEP(xq.y)
        STEP(xq.z)
        STEP(xq.w)
    }
#undef STEP

    // ---- final projection: out[b] = b_fc + h . W_fc ----
    if (lane == 0) {
        float acc = b_fc[0];
        #pragma unroll
        for (int k = 0; k < HID; ++k)
            acc = fmaf(hs[w][k], W_fc[k], acc);
        out[b] = acc;
    }
}

extern "C" void kernel_launch(void* const* d_in, const int* in_sizes, int n_in,
                              void* d_out, int out_size, void* d_ws, size_t ws_size,
                              hipStream_t stream) {
    const float* batch = (const float*)d_in[0];
    const float* W_ih  = (const float*)d_in[1];
    const float* W_hh  = (const float*)d_in[2];
    const float* b_ih  = (const float*)d_in[3];
    const float* b_hh  = (const float*)d_in[4];
    const float* W_fc  = (const float*)d_in[5];
    const float* b_fc  = (const float*)d_in[6];
    float* out = (float*)d_out;

    const int blocks = 8192 / WPB;   // 2048
    lstm_kernel<<<blocks, 256, 0, stream>>>(batch, W_ih, W_hh, b_ih, b_hh,
                                            W_fc, b_fc, out);
}

// Round 7
// 480.979 us; speedup vs baseline: 1.2947x; 1.1291x over previous
//
#include <hip/hip_runtime.h>

#define HID 30
#define TS  512
#define WPB 4   // waves (= batch elements) per 256-thread block
#define LOG2E 1.44269504088896340736f

typedef float f4 __attribute__((ext_vector_type(4)));

__global__ __launch_bounds__(256, 4)
void lstm_kernel(const float* __restrict__ batch,
                 const float* __restrict__ W_ih,
                 const float* __restrict__ W_hh,
                 const float* __restrict__ b_ih,
                 const float* __restrict__ b_hh,
                 const float* __restrict__ W_fc,
                 const float* __restrict__ b_fc,
                 float* __restrict__ out)
{
    __shared__ float xs[WPB][TS];                   // 8 KB x rows
    __shared__ __align__(16) float hs[WPB][32];     // h state (fp32)

    const int tid  = threadIdx.x;
    const int w    = tid >> 6;
    const int lane = tid & 63;
    const int half = lane >> 5;         // 0: gates i,f   1: gates g,o
    const int j    = lane & 31;
    const int jj   = (j < HID) ? j : (HID - 1);
    const int b    = blockIdx.x * WPB + w;

    // ---- per-wave x staging (coalesced; wave-private -> no barrier) ----
    const float* src = batch + (size_t)b * TS;
    #pragma unroll
    for (int i = 0; i < TS / 64; ++i)
        xs[w][lane + i * 64] = src[lane + i * 64];

    hs[w][j] = 0.0f;   // init h (all 32 slots; dup writes benign)

    // ---- per-lane weights, prescaled, as 60 NAMED SCALARS ----
    // row0: gate i (half0, sigmoid, scale -L) / g (half1, tanh, scale -2L)
    // row1: gate f / o (sigmoid, scale -L)
    const int   row0 = jj + (half ? 2 * HID : 0);
    const int   row1 = row0 + HID;
    const float s0   = half ? (-2.0f * LOG2E) : (-LOG2E);
    const float s1   = -LOG2E;
    const float* wr0 = W_hh + row0 * HID;
    const float* wr1 = W_hh + row1 * HID;

#define DEFW(K) const float w0_##K = wr0[K] * s0; const float w1_##K = wr1[K] * s1;
    DEFW(0)  DEFW(1)  DEFW(2)  DEFW(3)  DEFW(4)  DEFW(5)
    DEFW(6)  DEFW(7)  DEFW(8)  DEFW(9)  DEFW(10) DEFW(11)
    DEFW(12) DEFW(13) DEFW(14) DEFW(15) DEFW(16) DEFW(17)
    DEFW(18) DEFW(19) DEFW(20) DEFW(21) DEFW(22) DEFW(23)
    DEFW(24) DEFW(25) DEFW(26) DEFW(27) DEFW(28) DEFW(29)
#undef DEFW

    const float bb0 = (b_ih[row0] + b_hh[row0]) * s0;
    const float bb1 = (b_ih[row1] + b_hh[row1]) * s1;
    const float xw0 = W_ih[row0] * s0;
    const float xw1 = W_ih[row1] * s1;

    // act0 = fma(am, rcp(1+exp2(a0)), aa):  half0 -> 2L*sigmoid (K-scaled i),
    //                                       half1 -> tanh (g)
    const float am = half ? 2.0f : (2.0f * LOG2E);
    const float aa = half ? -1.0f : 0.0f;
    const int swap4 = (lane ^ 32) << 2;   // bpermute partner (other half)

    const f4* hq4 = (const f4*)hs[w];
    float cp = 0.0f;                      // c scaled by 2L

#define DOTP(Q, C, K) p0 = fmaf(Q.C, w0_##K, p0); p1 = fmaf(Q.C, w1_##K, p1);
#define DOTQ(Q, C, K) q0 = fmaf(Q.C, w0_##K, q0); q1 = fmaf(Q.C, w1_##K, q1);

#define STEP(xv) { \
    const float x = (xv); \
    float p0 = fmaf(x, xw0, bb0), q0 = 0.0f; \
    float p1 = fmaf(x, xw1, bb1), q1 = 0.0f; \
    const f4 A0 = hq4[0], A1 = hq4[1], A2 = hq4[2], A3 = hq4[3]; \
    const f4 A4 = hq4[4], A5 = hq4[5], A6 = hq4[6], A7 = hq4[7]; \
    DOTP(A0,x,0)  DOTQ(A0,y,1)  DOTP(A0,z,2)  DOTQ(A0,w,3) \
    DOTP(A1,x,4)  DOTQ(A1,y,5)  DOTP(A1,z,6)  DOTQ(A1,w,7) \
    DOTP(A2,x,8)  DOTQ(A2,y,9)  DOTP(A2,z,10) DOTQ(A2,w,11) \
    DOTP(A3,x,12) DOTQ(A3,y,13) DOTP(A3,z,14) DOTQ(A3,w,15) \
    DOTP(A4,x,16) DOTQ(A4,y,17) DOTP(A4,z,18) DOTQ(A4,w,19) \
    DOTP(A5,x,20) DOTQ(A5,y,21) DOTP(A5,z,22) DOTQ(A5,w,23) \
    DOTP(A6,x,24) DOTQ(A6,y,25) DOTP(A6,z,26) DOTQ(A6,w,27) \
    DOTP(A7,x,28) DOTQ(A7,y,29) \
    const float a0 = p0 + q0; \
    const float a1 = p1 + q1; \
    float pa = fmaf(am, __builtin_amdgcn_rcpf(1.0f + __builtin_amdgcn_exp2f(a0)), aa); \
    float pb; \
    /* copy then swap: "=&v" early-clobber guarantees pb's reg != pa's reg. */ \
    /* After: pa = act0(own-half value) bcast, pb = act0(other half) bcast;  */ \
    /* only the symmetric product pa*pb = (2L*i)*g is consumed.             */ \
    asm volatile("v_mov_b32 %0, %1\n\t" \
                 "v_permlane32_swap_b32 %0, %1" \
                 : "=&v"(pb), "+v"(pa)); \
    const float act1 = __builtin_amdgcn_rcpf(1.0f + __builtin_amdgcn_exp2f(a1)); /* f|o */ \
    const float r1 = __int_as_float( \
        __builtin_amdgcn_ds_bpermute(swap4, __float_as_int(act1))); \
    const float fv = half ? r1 : act1; \
    const float ov = half ? act1 : r1; \
    cp = fmaf(fv, cp, pa * pb);          /* (2L*i)*g, order-agnostic */ \
    const float th = fmaf(-2.0f, \
        __builtin_amdgcn_rcpf(1.0f + __builtin_amdgcn_exp2f(cp)), 1.0f); \
    hs[w][j] = ov * th; \
}

    for (int t4 = 0; t4 < TS / 4; ++t4) {
        const f4 xq = ((const f4*)xs[w])[t4];
        STEP(xq.x)
        STEP(xq.y)
        STEP(xq.z)
        STEP(xq.w)
    }
#undef STEP
#undef DOTP
#undef DOTQ

    // ---- final projection: out[b] = b_fc + h . W_fc ----
    if (lane == 0) {
        float acc = b_fc[0];
        #pragma unroll
        for (int k = 0; k < HID; ++k)
            acc = fmaf(hs[w][k], W_fc[k], acc);
        out[b] = acc;
    }
}

extern "C" void kernel_launch(void* const* d_in, const int* in_sizes, int n_in,
                              void* d_out, int out_size, void* d_ws, size_t ws_size,
                              hipStream_t stream) {
    const float* batch = (const float*)d_in[0];
    const float* W_ih  = (const float*)d_in[1];
    const float* W_hh  = (const float*)d_in[2];
    const float* b_ih  = (const float*)d_in[3];
    const float* b_hh  = (const float*)d_in[4];
    const float* W_fc  = (const float*)d_in[5];
    const float* b_fc  = (const float*)d_in[6];
    float* out = (float*)d_out;

    const int blocks = 8192 / WPB;   // 2048
    lstm_kernel<<<blocks, 256, 0, stream>>>(batch, W_ih, W_hh, b_ih, b_hh,
                                            W_fc, b_fc, out);
}

// Round 8
// 363.399 us; speedup vs baseline: 1.7136x; 1.3236x over previous
//
#include <hip/hip_runtime.h>

#define HID 30
#define TS  512
#define NB  16     // batch elements per wave
#define LOG2E 1.44269504088896340736f

typedef __attribute__((ext_vector_type(8))) short bf16x8;
typedef __attribute__((ext_vector_type(4))) float f32x4;

__device__ __forceinline__ float rcp_f(float x) { return __builtin_amdgcn_rcpf(x); }
__device__ __forceinline__ float ex2_f(float x) { return __builtin_amdgcn_exp2f(x); }

__global__ __launch_bounds__(64)
void lstm_mfma_kernel(const float* __restrict__ batch,
                      const float* __restrict__ W_ih,
                      const float* __restrict__ W_hh,
                      const float* __restrict__ b_ih,
                      const float* __restrict__ b_hh,
                      const float* __restrict__ W_fc,
                      const float* __restrict__ b_fc,
                      float* __restrict__ out)
{
    __shared__ float xs[TS * NB];   // 32 KB: x transposed [t][n]

    const int tid  = threadIdx.x;   // == lane (64-thread block, one wave)
    const int q    = tid >> 4;      // k-group / row-group 0..3
    const int col  = tid & 15;      // batch col n / tile row
    const int b0   = blockIdx.x * NB;

    // ---- stage x: [16 rows x 512] -> xs[t][n], float4 global loads ----
    #pragma unroll
    for (int i = 0; i < 32; ++i) {
        const int flat = i * 64 + tid;        // float4-granule index 0..2047
        const int e    = flat >> 7;           // element row 0..15
        const int tq   = flat & 127;          // float4 pos within row
        const f32x4 v = ((const f32x4*)(batch + (size_t)(b0 + e) * TS))[tq];
        xs[(tq * 4 + 0) * NB + e] = v[0];
        xs[(tq * 4 + 1) * NB + e] = v[1];
        xs[(tq * 4 + 2) * NB + e] = v[2];
        xs[(tq * 4 + 3) * NB + e] = v[3];
    }

    // ---- build A fragments: W'[128][32], split hi/lo bf16 ----
    // grow = 16*mt + (l&15); gate G = mt>>1, parity P = mt&1
    // unit uA = 8*((l&15)>>2) + 4P + (l&3)  (sigma: zero-repack permutation)
    // k = (l>>4)*8 + jj;  k<30: W_hh, k==30: bias, k==31: W_ih; scaled
    bf16x8 a_hi[8], a_lo[8];
    #pragma unroll
    for (int mt = 0; mt < 8; ++mt) {
        const int G = mt >> 1, P = mt & 1;
        const int uA = 8 * (col >> 2) + 4 * P + (col & 3);
        const float sG = (G == 2) ? (-2.0f * LOG2E) : (-LOG2E);
        const int R = G * HID + uA;
        #pragma unroll
        for (int jj = 0; jj < 8; ++jj) {
            const int kk = q * 8 + jj;
            float wv = 0.0f;
            if (uA < HID) {
                if (kk < HID)       wv = W_hh[R * HID + kk];
                else if (kk == 30)  wv = b_ih[R] + b_hh[R];
                else                wv = W_ih[R];
            }
            wv *= sG;
            const __bf16 hi = (__bf16)wv;
            const __bf16 lo = (__bf16)(wv - (float)hi);
            a_hi[mt][jj] = (short)__builtin_bit_cast(unsigned short, hi);
            a_lo[mt][jj] = (short)__builtin_bit_cast(unsigned short, lo);
        }
    }

    __builtin_amdgcn_s_waitcnt(0);   // LDS writes visible to own wave
    // (single wave per block: no barrier needed)

    const float TWOL = 2.0f * LOG2E;
    const f32x4 ZERO4 = {0.0f, 0.0f, 0.0f, 0.0f};

    float cm[8], hreg[8];
    #pragma unroll
    for (int ii = 0; ii < 8; ++ii) { cm[ii] = 0.0f; hreg[ii] = 0.0f; }

    float xv = xs[0 * NB + col];

    for (int t = 0; t < TS; ++t) {
        const float xnext = xs[(((t + 1) & (TS - 1)) * NB) + col];

        // ---- build B fragment from h (+ slots 30:=1.0, 31:=x), split hi/lo
        bf16x8 bhi, blo;
        #pragma unroll
        for (int r2 = 0; r2 < 8; ++r2) {
            const __bf16 hb = (__bf16)hreg[r2];
            const __bf16 lb = (__bf16)(hreg[r2] - (float)hb);
            bhi[r2] = (short)__builtin_bit_cast(unsigned short, hb);
            blo[r2] = (short)__builtin_bit_cast(unsigned short, lb);
        }
        {
            const __bf16 xh = (__bf16)xv;
            const __bf16 xl = (__bf16)(xv - (float)xh);
            const short xhb = (short)__builtin_bit_cast(unsigned short, xh);
            const short xlb = (short)__builtin_bit_cast(unsigned short, xl);
            const bool top = (q == 3);
            bhi[6] = top ? (short)0x3F80 : bhi[6];   // bf16(1.0)
            bhi[7] = top ? xhb          : bhi[7];
            blo[6] = top ? (short)0     : blo[6];
            blo[7] = top ? xlb          : blo[7];
        }

        // ---- 8 M-tiles x 4 split products ----
        f32x4 acc[8];
        #pragma unroll
        for (int mt = 0; mt < 8; ++mt) {
            f32x4 tacc = ZERO4;
            tacc = __builtin_amdgcn_mfma_f32_16x16x32_bf16(a_lo[mt], blo, tacc, 0, 0, 0);
            tacc = __builtin_amdgcn_mfma_f32_16x16x32_bf16(a_lo[mt], bhi, tacc, 0, 0, 0);
            tacc = __builtin_amdgcn_mfma_f32_16x16x32_bf16(a_hi[mt], blo, tacc, 0, 0, 0);
            acc[mt] = __builtin_amdgcn_mfma_f32_16x16x32_bf16(a_hi[mt], bhi, tacc, 0, 0, 0);
        }

        // ---- activations + state update, all lane-local ----
        // prescales: i,f,o rows by -L, g rows by -2L; cm = -2L*c convention
        //   i = rcp(1+ei), g = (1-eg)/(1+eg)  ->  igm = -2L*i*g = 2L*(eg-1)/((1+ei)(1+eg))
        //   cm = fv*cm + igm ; tanh(c) = (1-e)/(1+e), e = exp2(cm)
        //   h = o*tanh(c) = (1-e) / ((1+e)(1+eo))
        #pragma unroll
        for (int ii = 0; ii < 8; ++ii) {
            const int P = ii >> 2, r = ii & 3;
            const float ai = acc[0 + P][r];
            const float af = acc[2 + P][r];
            const float ag = acc[4 + P][r];
            const float ao = acc[6 + P][r];
            const float ei = ex2_f(ai);
            const float eg = ex2_f(ag);
            const float rr = rcp_f((1.0f + ei) * (1.0f + eg));
            const float igm = TWOL * ((eg - 1.0f) * rr);
            const float fv = rcp_f(1.0f + ex2_f(af));
            cm[ii] = fmaf(fv, cm[ii], igm);
            const float e  = ex2_f(cm[ii]);
            const float eo = ex2_f(ao);
            const float r2 = rcp_f((1.0f + e) * (1.0f + eo));
            hreg[ii] = (1.0f - e) * r2;
        }

        xv = xnext;
    }

    // ---- final projection: out[b0+n] = b_fc + sum_u h[u]*W_fc[u] ----
    float part = 0.0f;
    #pragma unroll
    for (int ii = 0; ii < 8; ++ii) {
        const int u = 8 * q + ii;
        const float wf = (u < HID) ? W_fc[u] : 0.0f;
        part = fmaf(hreg[ii], wf, part);
    }
    part += __shfl_xor(part, 16);
    part += __shfl_xor(part, 32);
    if (tid < 16) out[b0 + tid] = part + b_fc[0];
}

extern "C" void kernel_launch(void* const* d_in, const int* in_sizes, int n_in,
                              void* d_out, int out_size, void* d_ws, size_t ws_size,
                              hipStream_t stream) {
    const float* batch = (const float*)d_in[0];
    const float* W_ih  = (const float*)d_in[1];
    const float* W_hh  = (const float*)d_in[2];
    const float* b_ih  = (const float*)d_in[3];
    const float* b_hh  = (const float*)d_in[4];
    const float* W_fc  = (const float*)d_in[5];
    const float* b_fc  = (const float*)d_in[6];
    float* out = (float*)d_out;

    const int blocks = 8192 / NB;   // 512 single-wave blocks
    lstm_mfma_kernel<<<blocks, 64, 0, stream>>>(batch, W_ih, W_hh, b_ih, b_hh,
                                                W_fc, b_fc, out);
}